// Round 2
// baseline (522.970 us; speedup 1.0000x reference)
//
#include <hip/hip_runtime.h>
#include <stdint.h>

// B=32, L1=L2=512, D=1024, fp32 in/out.
// sim GEMM: split-bf16 (hi/lo) x3 MFMA for fp32-like logit precision.
// P*V GEMMs: plain bf16 MFMA (error ~0.01-0.03, OK vs 0.104 threshold).
// ws layout (128 MiB peak):
//   [0]      v1t  bf16 [B][D][L1]  (32 MiB)
//   [32Mi]   v2t  bf16 [B][D][L2]  (32 MiB)
//   [64Mi]   sim  fp32 [B][L1][L2] (32 MiB)
//   [96Mi]   A1   bf16 [B][L1][L2] (16 MiB)
//   [112Mi]  A2t  bf16 [B][L2][L1] (16 MiB)

#define Bn 32
#define Ln 512
#define Dn 1024

typedef __attribute__((ext_vector_type(4))) float f32x4;
typedef __attribute__((ext_vector_type(4))) unsigned short u16x4;
typedef __attribute__((ext_vector_type(8))) unsigned short u16x8;
typedef __attribute__((ext_vector_type(8))) __bf16 bf16x8;

union bfcast { u16x8 u; bf16x8 b; };

__device__ __forceinline__ unsigned short f2bf(float f) {  // RNE
  unsigned int u = __float_as_uint(f);
  u += 0x7FFFu + ((u >> 16) & 1u);
  return (unsigned short)(u >> 16);
}

__device__ __forceinline__ void async_cp16(const void* g, void* l) {
  __builtin_amdgcn_global_load_lds(
      (__attribute__((address_space(1))) void*)(g),
      (__attribute__((address_space(3))) void*)(l), 16, 0, 0);
}

// split 8 fp32 -> hi/lo bf16 (truncation split; residual <= 2^-16 * |a|)
__device__ __forceinline__ void cvt8(f32x4 x0, f32x4 x1,
                                     bf16x8* hi, bf16x8* lo) {
  float xs[8] = {x0[0], x0[1], x0[2], x0[3], x1[0], x1[1], x1[2], x1[3]};
  u16x8 h, l;
#pragma unroll
  for (int e = 0; e < 8; e++) {
    unsigned int u = __float_as_uint(xs[e]);
    h[e] = (unsigned short)(u >> 16);
    float hf = __uint_as_float(u & 0xFFFF0000u);
    l[e] = (unsigned short)(__float_as_uint(xs[e] - hf) >> 16);
  }
  bfcast ch, cl;
  ch.u = h; cl.u = l;
  *hi = ch.b; *lo = cl.b;
}

// ---- fp32 -> bf16 transpose only: vXt[b][d][l] = bf16(vX[b][l][d]) ----
// grid (Dn/64=16, Ln/64=8, 2*Bn=64)
__global__ __launch_bounds__(256) void conv_t(
    const float* __restrict__ v1, const float* __restrict__ v2,
    unsigned short* __restrict__ v1t, unsigned short* __restrict__ v2t) {
  __shared__ float tile[64][65];
  const int z = blockIdx.z;
  const float* src = (z < Bn) ? v1 : v2;
  unsigned short* dt = (z < Bn) ? v1t : v2t;
  const int b = z & 31;
  const int d0 = blockIdx.x << 6;
  const int l0 = blockIdx.y << 6;
  const int tid = threadIdx.x;
#pragma unroll
  for (int it = 0; it < 4; it++) {
    int lin = (it << 8) + tid;
    int l = lin >> 4;
    int d4 = (lin & 15) << 2;
    f32x4 x = *(const f32x4*)(src + (size_t)(b * Ln + l0 + l) * Dn + d0 + d4);
    tile[l][d4] = x[0]; tile[l][d4 + 1] = x[1];
    tile[l][d4 + 2] = x[2]; tile[l][d4 + 3] = x[3];
  }
  __syncthreads();
#pragma unroll
  for (int it = 0; it < 4; it++) {
    int lin = (it << 8) + tid;
    int d = lin >> 4;
    int l4 = (lin & 15) << 2;
    u16x4 o;
    o[0] = f2bf(tile[l4][d]);     o[1] = f2bf(tile[l4 + 1][d]);
    o[2] = f2bf(tile[l4 + 2][d]); o[3] = f2bf(tile[l4 + 3][d]);
    *(u16x4*)(dt + (size_t)(b * Dn + d0 + d) * Ln + l0 + l4) = o;
  }
}

// ---- sim[b][i][j] = sum_d v1[i,d]*v2[j,d], split-bf16 (3 MFMA passes) ----
// 128x128 tile, BK=32 fp32, fp32 tiles staged via global_load_lds with
// XOR k-chunk swizzle (LDS[m][c] = global[m][c ^ (m&7)], c = 16B chunk).
// grid (4,4,32), 256 threads.
__global__ __launch_bounds__(256) void sim_gemm_split(
    const float* __restrict__ V1, const float* __restrict__ V2,
    float* __restrict__ C) {
  __shared__ float As[128 * 32];  // 16 KB
  __shared__ float Bs[128 * 32];  // 16 KB
  const int b = blockIdx.z;
  const float* Ab = V1 + (size_t)b * Ln * Dn;
  const float* Bb = V2 + (size_t)b * Ln * Dn;
  float* Cb = C + (size_t)b * Ln * Ln;
  const int m0 = blockIdx.y << 7;
  const int n0 = blockIdx.x << 7;
  const int tid = threadIdx.x;
  const int lane = tid & 63;
  const int wave = tid >> 6;
  const int wrow = (wave >> 1) << 6;
  const int wcol = (wave & 1) << 6;

  // staging: lane covers row (wave*32 + j*8 + lane/8), swizzled chunk
  const int srow = lane >> 3;                  // 0..7
  const int scol = ((lane & 7) ^ srow) << 2;   // swizzled fp32 offset
  const float* ga = Ab + (size_t)(m0 + (wave << 5) + srow) * Dn + scol;
  const float* gb = Bb + (size_t)(n0 + (wave << 5) + srow) * Dn + scol;

  const int r = lane & 15;
  const int q = lane >> 4;

  const f32x4 zero4 = {0.f, 0.f, 0.f, 0.f};
  f32x4 acc[4][4];
#pragma unroll
  for (int i = 0; i < 4; i++)
#pragma unroll
    for (int j = 0; j < 4; j++) acc[i][j] = zero4;

  for (int k0 = 0; k0 < Dn; k0 += 32) {
    __syncthreads();
#pragma unroll
    for (int j = 0; j < 4; j++) {
      async_cp16(ga + k0 + j * 8 * Dn, As + ((wave << 5) + j * 8) * 32);
      async_cp16(gb + k0 + j * 8 * Dn, Bs + ((wave << 5) + j * 8) * 32);
    }
    __syncthreads();
    bf16x8 ah[4], al[4], bh[4], bl[4];
#pragma unroll
    for (int t = 0; t < 4; t++) {
      int ra = wrow + (t << 4) + r;
      f32x4 x0 = *(const f32x4*)(As + ra * 32 + ((((q << 1)    ) ^ (ra & 7)) << 2));
      f32x4 x1 = *(const f32x4*)(As + ra * 32 + ((((q << 1) | 1) ^ (ra & 7)) << 2));
      cvt8(x0, x1, &ah[t], &al[t]);
      int rb = wcol + (t << 4) + r;
      f32x4 y0 = *(const f32x4*)(Bs + rb * 32 + ((((q << 1)    ) ^ (rb & 7)) << 2));
      f32x4 y1 = *(const f32x4*)(Bs + rb * 32 + ((((q << 1) | 1) ^ (rb & 7)) << 2));
      cvt8(y0, y1, &bh[t], &bl[t]);
    }
#pragma unroll
    for (int tm = 0; tm < 4; tm++)
#pragma unroll
      for (int tn = 0; tn < 4; tn++) {
        acc[tm][tn] = __builtin_amdgcn_mfma_f32_16x16x32_bf16(
            ah[tm], bh[tn], acc[tm][tn], 0, 0, 0);
        acc[tm][tn] = __builtin_amdgcn_mfma_f32_16x16x32_bf16(
            ah[tm], bl[tn], acc[tm][tn], 0, 0, 0);
        acc[tm][tn] = __builtin_amdgcn_mfma_f32_16x16x32_bf16(
            al[tm], bh[tn], acc[tm][tn], 0, 0, 0);
      }
  }

  // C/D layout: col = lane&15, row = (lane>>4)*4 + reg
#pragma unroll
  for (int tm = 0; tm < 4; tm++) {
    int rowb = m0 + wrow + (tm << 4) + (q << 2);
#pragma unroll
    for (int reg = 0; reg < 4; reg++) {
      int row = rowb + reg;
#pragma unroll
      for (int tn = 0; tn < 4; tn++) {
        int col = n0 + wcol + (tn << 4) + r;
        Cb[(size_t)row * Ln + col] = acc[tm][tn][reg];
      }
    }
  }
}

// ---- NT GEMM (bf16): C[b][m][n] = sum_k A[b][m][k]*B[b][n][k], fp32 out ----
// rowmask != null: zero rows where mask!=0.
__global__ __launch_bounds__(256) void gemm_nt(
    const unsigned short* __restrict__ A, const unsigned short* __restrict__ Bm,
    float* __restrict__ C, const int* __restrict__ rowmask,
    int M, int N, int K) {
  __shared__ unsigned short As[128 * 32];
  __shared__ unsigned short Bs[128 * 32];
  const int b = blockIdx.z;
  const unsigned short* Ab = A + (size_t)b * M * K;
  const unsigned short* Bb = Bm + (size_t)b * N * K;
  float* Cb = C + (size_t)b * M * N;
  const int m0 = blockIdx.y << 7;
  const int n0 = blockIdx.x << 7;
  const int tid = threadIdx.x;
  const int lane = tid & 63;
  const int wave = tid >> 6;
  const int wrow = (wave >> 1) << 6;
  const int wcol = (wave & 1) << 6;

  const int srow = tid >> 2;
  const int skof = (tid & 3) << 3;
  const unsigned short* ga0 = Ab + (size_t)(m0 + srow) * K + skof;
  const unsigned short* ga1 = Ab + (size_t)(m0 + 64 + srow) * K + skof;
  const unsigned short* gb0 = Bb + (size_t)(n0 + srow) * K + skof;
  const unsigned short* gb1 = Bb + (size_t)(n0 + 64 + srow) * K + skof;

  const int r = lane & 15;
  const int q = lane >> 4;

  const f32x4 zero4 = {0.f, 0.f, 0.f, 0.f};
  f32x4 acc[4][4];
#pragma unroll
  for (int i = 0; i < 4; i++)
#pragma unroll
    for (int j = 0; j < 4; j++) acc[i][j] = zero4;

  for (int k0 = 0; k0 < K; k0 += 32) {
    __syncthreads();
    async_cp16(ga0 + k0, As + (wave << 9));
    async_cp16(ga1 + k0, As + 2048 + (wave << 9));
    async_cp16(gb0 + k0, Bs + (wave << 9));
    async_cp16(gb1 + k0, Bs + 2048 + (wave << 9));
    __syncthreads();
    bf16x8 af[4], bf[4];
#pragma unroll
    for (int t = 0; t < 4; t++) {
      af[t] = *(const bf16x8*)(As + ((wrow + (t << 4) + r) << 5) + (q << 3));
      bf[t] = *(const bf16x8*)(Bs + ((wcol + (t << 4) + r) << 5) + (q << 3));
    }
#pragma unroll
    for (int tm = 0; tm < 4; tm++)
#pragma unroll
      for (int tn = 0; tn < 4; tn++)
        acc[tm][tn] = __builtin_amdgcn_mfma_f32_16x16x32_bf16(
            af[tm], bf[tn], acc[tm][tn], 0, 0, 0);
  }

  const int* mb = rowmask ? rowmask + b * M : (const int*)0;
#pragma unroll
  for (int tm = 0; tm < 4; tm++) {
    int rowb = m0 + wrow + (tm << 4) + (q << 2);
#pragma unroll
    for (int reg = 0; reg < 4; reg++) {
      int row = rowb + reg;
      float mz = (mb && mb[row]) ? 0.f : 1.f;
#pragma unroll
      for (int tn = 0; tn < 4; tn++) {
        int col = n0 + wcol + (tn << 4) + r;
        Cb[(size_t)row * N + col] = acc[tm][tn][reg] * mz;
      }
    }
  }
}

// ---- softmax over j (contiguous), masked by v2_mask; out bf16 ----
__global__ __launch_bounds__(256) void row_softmax(
    const float* __restrict__ sim, const int* __restrict__ v2m,
    unsigned short* __restrict__ A1) {
  const int row = (blockIdx.x << 2) + (threadIdx.x >> 6);
  const int lane = threadIdx.x & 63;
  const int b = row >> 9;
  const float* s = sim + (size_t)row * Ln;
  const int* mk = v2m + (b << 9);
  const float NEGINF = -__builtin_inff();
  float v[8];
  float mx = NEGINF;
#pragma unroll
  for (int t = 0; t < 8; t++) {
    int j = lane + (t << 6);
    float x = mk[j] ? NEGINF : s[j];
    v[t] = x;
    mx = fmaxf(mx, x);
  }
#pragma unroll
  for (int off = 32; off > 0; off >>= 1) mx = fmaxf(mx, __shfl_xor(mx, off));
  float sum = 0.f;
#pragma unroll
  for (int t = 0; t < 8; t++) {
    float e = (v[t] > NEGINF) ? __expf(v[t] - mx) : 0.f;
    v[t] = e;
    sum += e;
  }
#pragma unroll
  for (int off = 32; off > 0; off >>= 1) sum += __shfl_xor(sum, off);
  float rs = 1.f / sum;
  unsigned short* o = A1 + (size_t)row * Ln;
#pragma unroll
  for (int t = 0; t < 8; t++) o[lane + (t << 6)] = f2bf(v[t] * rs);
}

// ---- softmax over i (strided), masked by v1_mask; out transposed bf16 ----
__global__ __launch_bounds__(256) void col_softmax_t(
    const float* __restrict__ sim, const int* __restrict__ v1m,
    unsigned short* __restrict__ A2t) {
  __shared__ float red[4][64];
  __shared__ float crs[64];
  __shared__ unsigned short Tc[64][66];
  const int b = blockIdx.y;
  const int j0 = blockIdx.x << 6;
  const int tx = threadIdx.x & 63;
  const int ty = threadIdx.x >> 6;
  const float* S = sim + (size_t)b * (Ln * Ln) + j0;
  const int* mk = v1m + (b << 9);
  const float NEGINF = -__builtin_inff();

  float mx = NEGINF;
  for (int i = ty; i < Ln; i += 4) {
    float x = S[(size_t)i * Ln + tx];
    if (!mk[i]) mx = fmaxf(mx, x);
  }
  red[ty][tx] = mx;
  __syncthreads();
  mx = fmaxf(fmaxf(red[0][tx], red[1][tx]), fmaxf(red[2][tx], red[3][tx]));
  __syncthreads();
  float sum = 0.f;
  for (int i = ty; i < Ln; i += 4) {
    float x = S[(size_t)i * Ln + tx];
    sum += mk[i] ? 0.f : __expf(x - mx);
  }
  red[ty][tx] = sum;
  __syncthreads();
  if (ty == 0)
    crs[tx] = 1.f / (red[0][tx] + red[1][tx] + red[2][tx] + red[3][tx]);
  __syncthreads();
  const float rs = crs[tx];
  unsigned short* o = A2t + ((size_t)(b << 9) + j0) * Ln;
  for (int ic = 0; ic < Ln; ic += 64) {
#pragma unroll
    for (int k = 0; k < 16; k++) {
      int i = ic + (k << 2) + ty;
      float x = S[(size_t)i * Ln + tx];
      float e = mk[i] ? 0.f : __expf(x - mx) * rs;
      Tc[tx][(k << 2) + ty] = f2bf(e);
    }
    __syncthreads();
#pragma unroll
    for (int t = 0; t < 16; t++) {
      int idx = (t << 8) + (int)threadIdx.x;
      int j = idx >> 6;
      int il = idx & 63;
      o[(size_t)j * Ln + ic + il] = Tc[j][il];
    }
    __syncthreads();
  }
}

extern "C" void kernel_launch(void* const* d_in, const int* in_sizes, int n_in,
                              void* d_out, int out_size, void* d_ws,
                              size_t ws_size, hipStream_t stream) {
  (void)in_sizes; (void)n_in; (void)out_size; (void)ws_size;
  const float* v1 = (const float*)d_in[0];
  const float* v2 = (const float*)d_in[1];
  const int* v1m = (const int*)d_in[2];
  const int* v2m = (const int*)d_in[3];
  float* out1 = (float*)d_out;
  float* out2 = out1 + (size_t)Bn * Ln * Dn;

  char* ws = (char*)d_ws;
  const size_t Mi = 1048576;
  unsigned short* v1t = (unsigned short*)(ws);
  unsigned short* v2t = (unsigned short*)(ws + 32 * Mi);
  float* sim = (float*)(ws + 64 * Mi);
  unsigned short* A1 = (unsigned short*)(ws + 96 * Mi);
  unsigned short* A2t = (unsigned short*)(ws + 112 * Mi);

  dim3 blk(256);
  conv_t<<<dim3(16, 8, 64), blk, 0, stream>>>(v1, v2, v1t, v2t);
  sim_gemm_split<<<dim3(4, 4, 32), blk, 0, stream>>>(v1, v2, sim);
  row_softmax<<<dim3(4096), blk, 0, stream>>>(sim, v2m, A1);
  col_softmax_t<<<dim3(8, 32), blk, 0, stream>>>(sim, v1m, A2t);
  // attended_v1[b][i][d] = sum_j A1[i,j] v2t[d,j]; zero masked i rows
  gemm_nt<<<dim3(8, 4, 32), blk, 0, stream>>>(A1, v2t, out1, v1m,
                                              512, 1024, 512);
  // attended_v2[b][j][d] = sum_i A2t[j,i] v1t[d,i]; zero masked j rows
  gemm_nt<<<dim3(8, 4, 32), blk, 0, stream>>>(A2t, v1t, out2, v2m,
                                              512, 1024, 512);
}

// Round 3
// 424.569 us; speedup vs baseline: 1.2318x; 1.2318x over previous
//
#include <hip/hip_runtime.h>
#include <stdint.h>

// B=32, L1=L2=512, D=1024, fp32 in/out.
// sim GEMM: split-bf16 (hi/lo) x3 MFMA for fp32-like logit precision.
// P*V GEMMs: plain bf16 MFMA.
// Column softmax: 3-phase online-softmax (part -> combine -> write), 2048-way
// parallel instead of 256 blocks x 3 serial passes (R1: 123us latency-bound).
// ws layout (~129.2 MiB peak):
//   [0]       v1t  bf16 [B][D][L1]  (32 MiB)
//   [32Mi]    v2t  bf16 [B][D][L2]  (32 MiB)
//   [64Mi]    sim  fp32 [B][L1][L2] (32 MiB)
//   [96Mi]    A1   bf16 [B][L1][L2] (16 MiB)
//   [112Mi]   A2t  bf16 [B][L2][L1] (16 MiB)
//   [128Mi]   pmax fp32 [B][8][512] (512 KiB)
//   [+512Ki]  psum fp32 [B][8][512] (512 KiB)
//   [129Mi]   cmax fp32 [B][512]    (64 KiB)
//   [+64Ki]   crs  fp32 [B][512]    (64 KiB)

#define Bn 32
#define Ln 512
#define Dn 1024

typedef __attribute__((ext_vector_type(4))) float f32x4;
typedef __attribute__((ext_vector_type(4))) unsigned short u16x4;
typedef __attribute__((ext_vector_type(8))) unsigned short u16x8;
typedef __attribute__((ext_vector_type(8))) __bf16 bf16x8;

union bfcast { u16x8 u; bf16x8 b; };

__device__ __forceinline__ unsigned short f2bf(float f) {  // RNE
  unsigned int u = __float_as_uint(f);
  u += 0x7FFFu + ((u >> 16) & 1u);
  return (unsigned short)(u >> 16);
}

__device__ __forceinline__ void async_cp16(const void* g, void* l) {
  __builtin_amdgcn_global_load_lds(
      (__attribute__((address_space(1))) void*)(g),
      (__attribute__((address_space(3))) void*)(l), 16, 0, 0);
}

// split 8 fp32 -> hi/lo bf16 (truncation split; residual <= 2^-16 * |a|)
__device__ __forceinline__ void cvt8(f32x4 x0, f32x4 x1,
                                     bf16x8* hi, bf16x8* lo) {
  float xs[8] = {x0[0], x0[1], x0[2], x0[3], x1[0], x1[1], x1[2], x1[3]};
  u16x8 h, l;
#pragma unroll
  for (int e = 0; e < 8; e++) {
    unsigned int u = __float_as_uint(xs[e]);
    h[e] = (unsigned short)(u >> 16);
    float hf = __uint_as_float(u & 0xFFFF0000u);
    l[e] = (unsigned short)(__float_as_uint(xs[e] - hf) >> 16);
  }
  bfcast ch, cl;
  ch.u = h; cl.u = l;
  *hi = ch.b; *lo = cl.b;
}

// ---- fp32 -> bf16 transpose only: vXt[b][d][l] = bf16(vX[b][l][d]) ----
__global__ __launch_bounds__(256) void conv_t(
    const float* __restrict__ v1, const float* __restrict__ v2,
    unsigned short* __restrict__ v1t, unsigned short* __restrict__ v2t) {
  __shared__ float tile[64][65];
  const int z = blockIdx.z;
  const float* src = (z < Bn) ? v1 : v2;
  unsigned short* dt = (z < Bn) ? v1t : v2t;
  const int b = z & 31;
  const int d0 = blockIdx.x << 6;
  const int l0 = blockIdx.y << 6;
  const int tid = threadIdx.x;
#pragma unroll
  for (int it = 0; it < 4; it++) {
    int lin = (it << 8) + tid;
    int l = lin >> 4;
    int d4 = (lin & 15) << 2;
    f32x4 x = *(const f32x4*)(src + (size_t)(b * Ln + l0 + l) * Dn + d0 + d4);
    tile[l][d4] = x[0]; tile[l][d4 + 1] = x[1];
    tile[l][d4 + 2] = x[2]; tile[l][d4 + 3] = x[3];
  }
  __syncthreads();
#pragma unroll
  for (int it = 0; it < 4; it++) {
    int lin = (it << 8) + tid;
    int d = lin >> 4;
    int l4 = (lin & 15) << 2;
    u16x4 o;
    o[0] = f2bf(tile[l4][d]);     o[1] = f2bf(tile[l4 + 1][d]);
    o[2] = f2bf(tile[l4 + 2][d]); o[3] = f2bf(tile[l4 + 3][d]);
    *(u16x4*)(dt + (size_t)(b * Dn + d0 + d) * Ln + l0 + l4) = o;
  }
}

// ---- sim[b][i][j] = sum_d v1[i,d]*v2[j,d], split-bf16 (3 MFMA passes) ----
__global__ __launch_bounds__(256) void sim_gemm_split(
    const float* __restrict__ V1, const float* __restrict__ V2,
    float* __restrict__ C) {
  __shared__ float As[128 * 32];
  __shared__ float Bs[128 * 32];
  const int b = blockIdx.z;
  const float* Ab = V1 + (size_t)b * Ln * Dn;
  const float* Bb = V2 + (size_t)b * Ln * Dn;
  float* Cb = C + (size_t)b * Ln * Ln;
  const int m0 = blockIdx.y << 7;
  const int n0 = blockIdx.x << 7;
  const int tid = threadIdx.x;
  const int lane = tid & 63;
  const int wave = tid >> 6;
  const int wrow = (wave >> 1) << 6;
  const int wcol = (wave & 1) << 6;

  const int srow = lane >> 3;
  const int scol = ((lane & 7) ^ srow) << 2;
  const float* ga = Ab + (size_t)(m0 + (wave << 5) + srow) * Dn + scol;
  const float* gb = Bb + (size_t)(n0 + (wave << 5) + srow) * Dn + scol;

  const int r = lane & 15;
  const int q = lane >> 4;

  const f32x4 zero4 = {0.f, 0.f, 0.f, 0.f};
  f32x4 acc[4][4];
#pragma unroll
  for (int i = 0; i < 4; i++)
#pragma unroll
    for (int j = 0; j < 4; j++) acc[i][j] = zero4;

  for (int k0 = 0; k0 < Dn; k0 += 32) {
    __syncthreads();
#pragma unroll
    for (int j = 0; j < 4; j++) {
      async_cp16(ga + k0 + j * 8 * Dn, As + ((wave << 5) + j * 8) * 32);
      async_cp16(gb + k0 + j * 8 * Dn, Bs + ((wave << 5) + j * 8) * 32);
    }
    __syncthreads();
    bf16x8 ah[4], al[4], bh[4], bl[4];
#pragma unroll
    for (int t = 0; t < 4; t++) {
      int ra = wrow + (t << 4) + r;
      f32x4 x0 = *(const f32x4*)(As + ra * 32 + ((((q << 1)    ) ^ (ra & 7)) << 2));
      f32x4 x1 = *(const f32x4*)(As + ra * 32 + ((((q << 1) | 1) ^ (ra & 7)) << 2));
      cvt8(x0, x1, &ah[t], &al[t]);
      int rb = wcol + (t << 4) + r;
      f32x4 y0 = *(const f32x4*)(Bs + rb * 32 + ((((q << 1)    ) ^ (rb & 7)) << 2));
      f32x4 y1 = *(const f32x4*)(Bs + rb * 32 + ((((q << 1) | 1) ^ (rb & 7)) << 2));
      cvt8(y0, y1, &bh[t], &bl[t]);
    }
#pragma unroll
    for (int tm = 0; tm < 4; tm++)
#pragma unroll
      for (int tn = 0; tn < 4; tn++) {
        acc[tm][tn] = __builtin_amdgcn_mfma_f32_16x16x32_bf16(
            ah[tm], bh[tn], acc[tm][tn], 0, 0, 0);
        acc[tm][tn] = __builtin_amdgcn_mfma_f32_16x16x32_bf16(
            ah[tm], bl[tn], acc[tm][tn], 0, 0, 0);
        acc[tm][tn] = __builtin_amdgcn_mfma_f32_16x16x32_bf16(
            al[tm], bh[tn], acc[tm][tn], 0, 0, 0);
      }
  }

#pragma unroll
  for (int tm = 0; tm < 4; tm++) {
    int rowb = m0 + wrow + (tm << 4) + (q << 2);
#pragma unroll
    for (int reg = 0; reg < 4; reg++) {
      int row = rowb + reg;
#pragma unroll
      for (int tn = 0; tn < 4; tn++) {
        int col = n0 + wcol + (tn << 4) + r;
        Cb[(size_t)row * Ln + col] = acc[tm][tn][reg];
      }
    }
  }
}

// ---- NT GEMM (bf16): C[b][m][n] = sum_k A[b][m][k]*B[b][n][k], fp32 out ----
__global__ __launch_bounds__(256) void gemm_nt(
    const unsigned short* __restrict__ A, const unsigned short* __restrict__ Bm,
    float* __restrict__ C, const int* __restrict__ rowmask,
    int M, int N, int K) {
  __shared__ unsigned short As[128 * 32];
  __shared__ unsigned short Bs[128 * 32];
  const int b = blockIdx.z;
  const unsigned short* Ab = A + (size_t)b * M * K;
  const unsigned short* Bb = Bm + (size_t)b * N * K;
  float* Cb = C + (size_t)b * M * N;
  const int m0 = blockIdx.y << 7;
  const int n0 = blockIdx.x << 7;
  const int tid = threadIdx.x;
  const int lane = tid & 63;
  const int wave = tid >> 6;
  const int wrow = (wave >> 1) << 6;
  const int wcol = (wave & 1) << 6;

  const int srow = tid >> 2;
  const int skof = (tid & 3) << 3;
  const unsigned short* ga0 = Ab + (size_t)(m0 + srow) * K + skof;
  const unsigned short* ga1 = Ab + (size_t)(m0 + 64 + srow) * K + skof;
  const unsigned short* gb0 = Bb + (size_t)(n0 + srow) * K + skof;
  const unsigned short* gb1 = Bb + (size_t)(n0 + 64 + srow) * K + skof;

  const int r = lane & 15;
  const int q = lane >> 4;

  const f32x4 zero4 = {0.f, 0.f, 0.f, 0.f};
  f32x4 acc[4][4];
#pragma unroll
  for (int i = 0; i < 4; i++)
#pragma unroll
    for (int j = 0; j < 4; j++) acc[i][j] = zero4;

  for (int k0 = 0; k0 < K; k0 += 32) {
    __syncthreads();
    async_cp16(ga0 + k0, As + (wave << 9));
    async_cp16(ga1 + k0, As + 2048 + (wave << 9));
    async_cp16(gb0 + k0, Bs + (wave << 9));
    async_cp16(gb1 + k0, Bs + 2048 + (wave << 9));
    __syncthreads();
    bf16x8 af[4], bf[4];
#pragma unroll
    for (int t = 0; t < 4; t++) {
      af[t] = *(const bf16x8*)(As + ((wrow + (t << 4) + r) << 5) + (q << 3));
      bf[t] = *(const bf16x8*)(Bs + ((wcol + (t << 4) + r) << 5) + (q << 3));
    }
#pragma unroll
    for (int tm = 0; tm < 4; tm++)
#pragma unroll
      for (int tn = 0; tn < 4; tn++)
        acc[tm][tn] = __builtin_amdgcn_mfma_f32_16x16x32_bf16(
            af[tm], bf[tn], acc[tm][tn], 0, 0, 0);
  }

  const int* mb = rowmask ? rowmask + b * M : (const int*)0;
#pragma unroll
  for (int tm = 0; tm < 4; tm++) {
    int rowb = m0 + wrow + (tm << 4) + (q << 2);
#pragma unroll
    for (int reg = 0; reg < 4; reg++) {
      int row = rowb + reg;
      float mz = (mb && mb[row]) ? 0.f : 1.f;
#pragma unroll
      for (int tn = 0; tn < 4; tn++) {
        int col = n0 + wcol + (tn << 4) + r;
        Cb[(size_t)row * N + col] = acc[tm][tn][reg] * mz;
      }
    }
  }
}

// ---- softmax over j (contiguous), masked by v2_mask; out bf16 ----
__global__ __launch_bounds__(256) void row_softmax(
    const float* __restrict__ sim, const int* __restrict__ v2m,
    unsigned short* __restrict__ A1) {
  const int row = (blockIdx.x << 2) + (threadIdx.x >> 6);
  const int lane = threadIdx.x & 63;
  const int b = row >> 9;
  const float* s = sim + (size_t)row * Ln;
  const int* mk = v2m + (b << 9);
  const float NEGINF = -__builtin_inff();
  float v[8];
  float mx = NEGINF;
#pragma unroll
  for (int t = 0; t < 8; t++) {
    int j = lane + (t << 6);
    float x = mk[j] ? NEGINF : s[j];
    v[t] = x;
    mx = fmaxf(mx, x);
  }
#pragma unroll
  for (int off = 32; off > 0; off >>= 1) mx = fmaxf(mx, __shfl_xor(mx, off));
  float sum = 0.f;
#pragma unroll
  for (int t = 0; t < 8; t++) {
    float e = (v[t] > NEGINF) ? __expf(v[t] - mx) : 0.f;
    v[t] = e;
    sum += e;
  }
#pragma unroll
  for (int off = 32; off > 0; off >>= 1) sum += __shfl_xor(sum, off);
  float rs = 1.f / sum;
  unsigned short* o = A1 + (size_t)row * Ln;
#pragma unroll
  for (int t = 0; t < 8; t++) o[lane + (t << 6)] = f2bf(v[t] * rs);
}

// ---- column softmax phase 1: per-(64j x 64i)-tile online max/sum ----
// grid (8 jc, 8 ic, 32 b), 256 thr. pmax/psum [B][8][512]
__global__ __launch_bounds__(256) void csm_part(
    const float* __restrict__ sim, const int* __restrict__ v1m,
    float* __restrict__ pmax, float* __restrict__ psum) {
  __shared__ float sm[4][64], ss[4][64];
  const int b = blockIdx.z;
  const int ic = blockIdx.y;
  const int i0 = ic << 6;
  const int j0 = blockIdx.x << 6;
  const int tx = threadIdx.x & 63;
  const int ty = threadIdx.x >> 6;
  const float* S = sim + (size_t)b * (Ln * Ln) + j0 + tx;
  const int* mk = v1m + (b << 9) + i0;
  const float NEGINF = -__builtin_inff();
  float x[16];
#pragma unroll
  for (int k = 0; k < 16; k++) {
    int il = (k << 2) + ty;
    float v = S[(size_t)(i0 + il) * Ln];
    x[k] = mk[il] ? NEGINF : v;
  }
  float m = NEGINF;
#pragma unroll
  for (int k = 0; k < 16; k++) m = fmaxf(m, x[k]);
  float s = 0.f;
#pragma unroll
  for (int k = 0; k < 16; k++) s += (x[k] > NEGINF) ? __expf(x[k] - m) : 0.f;
  sm[ty][tx] = m;
  ss[ty][tx] = s;
  __syncthreads();
  if (ty == 0) {
    float M = fmaxf(fmaxf(sm[0][tx], sm[1][tx]), fmaxf(sm[2][tx], sm[3][tx]));
    float Sv = 0.f;
#pragma unroll
    for (int p = 0; p < 4; p++)
      Sv += (sm[p][tx] > NEGINF) ? ss[p][tx] * __expf(sm[p][tx] - M) : 0.f;
    int idx = (((b << 3) + ic) << 9) + j0 + tx;
    pmax[idx] = M;
    psum[idx] = Sv;
  }
}

// ---- column softmax phase 2: combine 8 partials per column ----
// grid (64), 256 thr: one column per thread. cmax/crs [B][512]
__global__ __launch_bounds__(256) void csm_comb(
    const float* __restrict__ pmax, const float* __restrict__ psum,
    float* __restrict__ cmax, float* __restrict__ crs) {
  const int col = (blockIdx.x << 8) + threadIdx.x;  // b*512 + j
  const int b = col >> 9;
  const int j = col & 511;
  const float NEGINF = -__builtin_inff();
  float mm[8], sv[8];
#pragma unroll
  for (int p = 0; p < 8; p++) {
    int idx = (((b << 3) + p) << 9) + j;
    mm[p] = pmax[idx];
    sv[p] = psum[idx];
  }
  float M = NEGINF;
#pragma unroll
  for (int p = 0; p < 8; p++) M = fmaxf(M, mm[p]);
  float Sv = 0.f;
#pragma unroll
  for (int p = 0; p < 8; p++)
    Sv += (mm[p] > NEGINF) ? sv[p] * __expf(mm[p] - M) : 0.f;
  cmax[col] = M;
  crs[col] = 1.f / Sv;
}

// ---- column softmax phase 3: write A2t[b][j][i] = bf16(exp*rs) ----
// grid (8 jc, 8 ic, 32 b), 256 thr
__global__ __launch_bounds__(256) void csm_write(
    const float* __restrict__ sim, const int* __restrict__ v1m,
    const float* __restrict__ cmax, const float* __restrict__ crs,
    unsigned short* __restrict__ A2t) {
  __shared__ float cm[64], cr[64];
  __shared__ unsigned short Tc[64][66];
  const int b = blockIdx.z;
  const int i0 = blockIdx.y << 6;
  const int j0 = blockIdx.x << 6;
  const int tx = threadIdx.x & 63;
  const int ty = threadIdx.x >> 6;
  if (threadIdx.x < 64) {
    cm[threadIdx.x] = cmax[(b << 9) + j0 + threadIdx.x];
    cr[threadIdx.x] = crs[(b << 9) + j0 + threadIdx.x];
  }
  __syncthreads();
  const float* S = sim + (size_t)b * (Ln * Ln) + j0 + tx;
  const int* mk = v1m + (b << 9) + i0;
  const float cmx = cm[tx];
  const float cs = cr[tx];
#pragma unroll
  for (int k = 0; k < 16; k++) {
    int il = (k << 2) + ty;
    float x = S[(size_t)(i0 + il) * Ln];
    float e = mk[il] ? 0.f : __expf(x - cmx) * cs;
    Tc[tx][il] = f2bf(e);
  }
  __syncthreads();
  unsigned short* o = A2t + ((size_t)(b << 9) + j0) * Ln + i0;
#pragma unroll
  for (int t = 0; t < 4; t++) {
    int c = (t << 8) + (int)threadIdx.x;
    int j = c >> 4;
    int ch = c & 15;
    u16x4 v;
    v[0] = Tc[j][(ch << 2)];     v[1] = Tc[j][(ch << 2) + 1];
    v[2] = Tc[j][(ch << 2) + 2]; v[3] = Tc[j][(ch << 2) + 3];
    *(u16x4*)(o + (size_t)j * Ln + (ch << 2)) = v;
  }
}

extern "C" void kernel_launch(void* const* d_in, const int* in_sizes, int n_in,
                              void* d_out, int out_size, void* d_ws,
                              size_t ws_size, hipStream_t stream) {
  (void)in_sizes; (void)n_in; (void)out_size; (void)ws_size;
  const float* v1 = (const float*)d_in[0];
  const float* v2 = (const float*)d_in[1];
  const int* v1m = (const int*)d_in[2];
  const int* v2m = (const int*)d_in[3];
  float* out1 = (float*)d_out;
  float* out2 = out1 + (size_t)Bn * Ln * Dn;

  char* ws = (char*)d_ws;
  const size_t Mi = 1048576;
  unsigned short* v1t = (unsigned short*)(ws);
  unsigned short* v2t = (unsigned short*)(ws + 32 * Mi);
  float* sim = (float*)(ws + 64 * Mi);
  unsigned short* A1 = (unsigned short*)(ws + 96 * Mi);
  unsigned short* A2t = (unsigned short*)(ws + 112 * Mi);
  float* pmax = (float*)(ws + 128 * Mi);
  float* psum = (float*)(ws + 128 * Mi + 512 * 1024);
  float* cmax = (float*)(ws + 129 * Mi);
  float* crs = (float*)(ws + 129 * Mi + 64 * 1024);

  dim3 blk(256);
  conv_t<<<dim3(16, 8, 64), blk, 0, stream>>>(v1, v2, v1t, v2t);
  sim_gemm_split<<<dim3(4, 4, 32), blk, 0, stream>>>(v1, v2, sim);
  row_softmax<<<dim3(4096), blk, 0, stream>>>(sim, v2m, A1);
  csm_part<<<dim3(8, 8, 32), blk, 0, stream>>>(sim, v1m, pmax, psum);
  csm_comb<<<dim3(64), blk, 0, stream>>>(pmax, psum, cmax, crs);
  csm_write<<<dim3(8, 8, 32), blk, 0, stream>>>(sim, v1m, cmax, crs, A2t);
  // attended_v1[b][i][d] = sum_j A1[i,j] v2t[d,j]; zero masked i rows
  gemm_nt<<<dim3(8, 4, 32), blk, 0, stream>>>(A1, v2t, out1, v1m,
                                              512, 1024, 512);
  // attended_v2[b][j][d] = sum_i A2t[j,i] v1t[d,i]; zero masked j rows
  gemm_nt<<<dim3(8, 4, 32), blk, 0, stream>>>(A2t, v1t, out2, v2m,
                                              512, 1024, 512);
}